// Round 14
// baseline (193.316 us; speedup 1.0000x reference)
//
#include <hip/hip_runtime.h>

#define NN 100000
#define NE 1250000
#define NWIN 782                      // ceil(NN/128) dst windows of 128 nodes
#define GA 256                        // pass-A writer blocks (private staging columns)
#define CHUNK ((NE + GA - 1) / GA)    // 4883 edges per writer block
#define CAP16 16                      // staging cap per (writer, window) cell (mean 6.2)
#define OVFCAP 131072                 // spill-list capacity (expect ~350 entries)
#define WEDCAP 40                     // max tracked degree per dst (mean 12.5)

typedef __attribute__((ext_vector_type(4))) float f32x4;
typedef __attribute__((ext_vector_type(8))) short s16x8;

// RNE float -> bf16 bits
__device__ __forceinline__ short bfb(float f) {
    union { float f; unsigned u; } c; c.f = f;
    unsigned u = c.u + 0x7fffu + ((c.u >> 16) & 1u);
    return (short)(u >> 16);
}
// hi/lo bf16 split: v ~= hi + lo, residual ~2^-17 * |v|
__device__ __forceinline__ void splitbf(float v, short& hi, short& lo) {
    hi = bfb(v);
    union { unsigned u; float f; } c; c.u = ((unsigned)(unsigned short)hi) << 16;
    lo = bfb(v - c.f);
}
__device__ __forceinline__ float lo2f(unsigned u) {
    union { unsigned u; float f; } c; c.u = u << 16; return c.f;
}
__device__ __forceinline__ float hi2f(unsigned u) {
    union { unsigned u; float f; } c; c.u = u & 0xffff0000u; return c.f;
}

// ---------------------------------------------------------------------------
// K_prep: pack weights into fragment-ordered bf16; zero the spill counter.
// ---------------------------------------------------------------------------
__global__ __launch_bounds__(256) void k_prep(
    const float* __restrict__ Wi, const float* __restrict__ Wl,
    const float* __restrict__ Ws, const float* __restrict__ Wo,
    short* __restrict__ P, int* __restrict__ ovf_cnt)
{
    const int t = blockIdx.x * 256 + threadIdx.x;
    if (t == 0) *ovf_cnt = 0;
    if (t >= 2048) return;
    const int mat = t >> 9, rem = t & 511;
    const int lane = rem & 63, cfg = rem >> 6;
    const int kh = cfg >> 2, nt = cfg & 3;
    const int m = lane & 15, q = lane >> 4;
    const float* W = mat == 0 ? Wi : mat == 1 ? Wl : mat == 2 ? Ws : Wo;
    s16x8 v;
    #pragma unroll
    for (int i = 0; i < 8; ++i)
        v[i] = bfb(W[(kh * 32 + q * 8 + i) * 64 + nt * 16 + m]);
    *(s16x8*)&P[(size_t)t * 8] = v;
}

// ---------------------------------------------------------------------------
// K1 (MFMA): h = relu(x@W_in+b_in); asrc = h@W_src; xlin = h@W_lin.
// EDGE-MLP FACTORIZATION (r13-proven): sp = p_s@Wp folded into the node row:
//   A' = asrc + sp,  X' = xlin - sp
// AXb[n*64+c] = pack(bf16(A') | bf16(X')<<16).
// ---------------------------------------------------------------------------
__global__ __launch_bounds__(256) void k_node_in(
    const float* __restrict__ x, const short* __restrict__ P,
    const float* __restrict__ b_in,
    const float* __restrict__ pos, const float* __restrict__ W_pos,
    unsigned* __restrict__ AXb)
{
    __shared__ float hT[4][16 * 68];
    const int lane = threadIdx.x & 63;
    const int wid  = threadIdx.x >> 6;
    const int m = lane & 15, q = lane >> 4;

    s16x8 Wf[3][2][4];
    #pragma unroll
    for (int mat = 0; mat < 3; ++mat)
        #pragma unroll
        for (int kh = 0; kh < 2; ++kh)
            #pragma unroll
            for (int nt = 0; nt < 4; ++nt)
                Wf[mat][kh][nt] = *(const s16x8*)&P[((size_t)mat * 512 + (kh * 4 + nt) * 64 + lane) * 8];
    float bin[4], wpv0[4], wpv1[4], wpv2[4];
    #pragma unroll
    for (int nt = 0; nt < 4; ++nt) {
        bin[nt]  = b_in[nt * 16 + m];
        wpv0[nt] = W_pos[nt * 16 + m];
        wpv1[nt] = W_pos[64 + nt * 16 + m];
        wpv2[nt] = W_pos[128 + nt * 16 + m];
    }

    const int wave = blockIdx.x * 4 + wid, nw = gridDim.x * 4;
    for (int chunk = wave; chunk < NN / 16; chunk += nw) {
        const int r0 = chunk * 16;
        const float* xr = x + (size_t)(r0 + m) * 64;
        float xv[16];
        *(float4*)&xv[0]  = *(const float4*)(xr + q * 8);
        *(float4*)&xv[4]  = *(const float4*)(xr + q * 8 + 4);
        *(float4*)&xv[8]  = *(const float4*)(xr + 32 + q * 8);
        *(float4*)&xv[12] = *(const float4*)(xr + 32 + q * 8 + 4);
        s16x8 ahi0, alo0, ahi1, alo1;
        #pragma unroll
        for (int i = 0; i < 8; ++i) {
            short h, l;
            splitbf(xv[i], h, l);     ahi0[i] = h; alo0[i] = l;
            splitbf(xv[8 + i], h, l); ahi1[i] = h; alo1[i] = l;
        }
        #pragma unroll
        for (int nt = 0; nt < 4; ++nt) {
            f32x4 acc = {0.f, 0.f, 0.f, 0.f};
            acc = __builtin_amdgcn_mfma_f32_16x16x32_bf16(alo0, Wf[0][0][nt], acc, 0, 0, 0);
            acc = __builtin_amdgcn_mfma_f32_16x16x32_bf16(alo1, Wf[0][1][nt], acc, 0, 0, 0);
            acc = __builtin_amdgcn_mfma_f32_16x16x32_bf16(ahi0, Wf[0][0][nt], acc, 0, 0, 0);
            acc = __builtin_amdgcn_mfma_f32_16x16x32_bf16(ahi1, Wf[0][1][nt], acc, 0, 0, 0);
            #pragma unroll
            for (int r = 0; r < 4; ++r) {
                float hv = acc[r] + bin[nt];
                hT[wid][(q * 4 + r) * 68 + nt * 16 + m] = hv > 0.f ? hv : 0.f;
            }
        }
        float hv[16];
        *(float4*)&hv[0]  = *(const float4*)&hT[wid][m * 68 + q * 8];
        *(float4*)&hv[4]  = *(const float4*)&hT[wid][m * 68 + q * 8 + 4];
        *(float4*)&hv[8]  = *(const float4*)&hT[wid][m * 68 + 32 + q * 8];
        *(float4*)&hv[12] = *(const float4*)&hT[wid][m * 68 + 32 + q * 8 + 4];
        s16x8 hhi0, hlo0, hhi1, hlo1;
        #pragma unroll
        for (int i = 0; i < 8; ++i) {
            short h, l;
            splitbf(hv[i], h, l);     hhi0[i] = h; hlo0[i] = l;
            splitbf(hv[8 + i], h, l); hhi1[i] = h; hlo1[i] = l;
        }
        float px[4], py[4], pz[4];
        #pragma unroll
        for (int r = 0; r < 4; ++r) {
            const float* pp = pos + (size_t)(r0 + q * 4 + r) * 3;
            px[r] = pp[0]; py[r] = pp[1]; pz[r] = pp[2];
        }
        #pragma unroll
        for (int nt = 0; nt < 4; ++nt) {
            f32x4 aS = {0.f, 0.f, 0.f, 0.f}, aL = {0.f, 0.f, 0.f, 0.f};
            aS = __builtin_amdgcn_mfma_f32_16x16x32_bf16(hlo0, Wf[2][0][nt], aS, 0, 0, 0);
            aS = __builtin_amdgcn_mfma_f32_16x16x32_bf16(hlo1, Wf[2][1][nt], aS, 0, 0, 0);
            aS = __builtin_amdgcn_mfma_f32_16x16x32_bf16(hhi0, Wf[2][0][nt], aS, 0, 0, 0);
            aS = __builtin_amdgcn_mfma_f32_16x16x32_bf16(hhi1, Wf[2][1][nt], aS, 0, 0, 0);
            aL = __builtin_amdgcn_mfma_f32_16x16x32_bf16(hlo0, Wf[1][0][nt], aL, 0, 0, 0);
            aL = __builtin_amdgcn_mfma_f32_16x16x32_bf16(hlo1, Wf[1][1][nt], aL, 0, 0, 0);
            aL = __builtin_amdgcn_mfma_f32_16x16x32_bf16(hhi0, Wf[1][0][nt], aL, 0, 0, 0);
            aL = __builtin_amdgcn_mfma_f32_16x16x32_bf16(hhi1, Wf[1][1][nt], aL, 0, 0, 0);
            #pragma unroll
            for (int r = 0; r < 4; ++r) {
                const float sp = fmaf(px[r], wpv0[nt], fmaf(py[r], wpv1[nt], pz[r] * wpv2[nt]));
                const unsigned p = (unsigned)(unsigned short)bfb(aS[r] + sp)          // A'
                                 | ((unsigned)(unsigned short)bfb(aL[r] - sp) << 16); // X'
                AXb[(size_t)(r0 + q * 4 + r) * 64 + nt * 16 + m] = p;
            }
        }
    }
}

// ---------------------------------------------------------------------------
// K_passA (r12-proven): writer-major staging, line-exclusive 64-B cells,
// LDS counters, rare spill list. Zero hot device atomics.
// ---------------------------------------------------------------------------
__global__ __launch_bounds__(256) void k_passA(
    const int* __restrict__ ei, unsigned* __restrict__ stage, int* __restrict__ gcnt,
    int2* __restrict__ ovf, int* __restrict__ ovf_cnt)
{
    __shared__ int lcnt[NWIN];
    const int g = blockIdx.x;
    for (int i = threadIdx.x; i < NWIN; i += 256) lcnt[i] = 0;
    __syncthreads();
    unsigned* myStage = stage + (size_t)g * NWIN * CAP16;
    const int e0 = g * CHUNK;
    const int e1 = (e0 + CHUNK < NE) ? e0 + CHUNK : NE;
    for (int e = e0 + threadIdx.x; e < e1; e += 256) {
        const int s = ei[e], d = ei[NE + e];
        const int b = d >> 7;
        const int c = atomicAdd(&lcnt[b], 1);          // LDS atomic
        if (c < CAP16) {
            myStage[b * CAP16 + c] = (unsigned)s | ((unsigned)(d & 127) << 17);
        } else {
            const int o = atomicAdd(ovf_cnt, 1);       // rare (~350 total)
            if (o < OVFCAP) ovf[o] = make_int2(s, d);
        }
    }
    __syncthreads();
    for (int i = threadIdx.x; i < NWIN; i += 256)
        gcnt[i * GA + g] = lcnt[i] < CAP16 ? lcnt[i] : CAP16;
}

// ---------------------------------------------------------------------------
// K_passB (r12-proven): compact writer-major cells + spill list into per-dst
// slot rows in LDS; coalesced int4 dump. Consumer clamps garbage beyond deg.
// ---------------------------------------------------------------------------
__global__ __launch_bounds__(256) void k_passB(
    const unsigned* __restrict__ stage, const int* __restrict__ gcnt,
    const int2* __restrict__ ovf, const int* __restrict__ ovf_cnt,
    int* __restrict__ slots, int* __restrict__ deg)
{
    __shared__ int slotsL[128 * WEDCAP];   // 20480 B
    __shared__ int cntL[128];
    const int b = blockIdx.x;
    const int t = threadIdx.x;
    if (t < 128) cntL[t] = 0;
    __syncthreads();
    const int n = min(gcnt[b * GA + t], CAP16);
    const unsigned* cell = stage + (size_t)t * NWIN * CAP16 + b * CAP16;
    uint4 q0 = *(const uint4*)cell;
    uint4 q1 = *(const uint4*)(cell + 4);
    uint4 q2 = *(const uint4*)(cell + 8);
    uint4 q3 = *(const uint4*)(cell + 12);
    const unsigned eb[16] = {q0.x, q0.y, q0.z, q0.w, q1.x, q1.y, q1.z, q1.w,
                             q2.x, q2.y, q2.z, q2.w, q3.x, q3.y, q3.z, q3.w};
    #pragma unroll
    for (int i = 0; i < CAP16; ++i)
        if (i < n) {
            const int d7 = (int)(eb[i] >> 17);
            const int c = atomicAdd(&cntL[d7], 1);      // LDS atomic, block-local
            if (c < WEDCAP) slotsL[d7 * WEDCAP + c] = (int)(eb[i] & 0x1ffff);
        }
    const int no = min(*ovf_cnt, OVFCAP);
    for (int i = t; i < no; i += 256) {
        const int2 sd = ovf[i];
        if ((sd.y >> 7) == b) {
            const int d7 = sd.y & 127;
            const int c = atomicAdd(&cntL[d7], 1);
            if (c < WEDCAP) slotsL[d7 * WEDCAP + c] = sd.x;
        }
    }
    __syncthreads();
    int4* dstq = (int4*)(slots + (size_t)b * 128 * WEDCAP);
    const int4* srcq = (const int4*)slotsL;
    #pragma unroll
    for (int i = 0; i < 5; ++i) dstq[i * 256 + t] = srcq[i * 256 + t];
    if (t < 128) {
        const int d = (b << 7) + t;
        if (d < NN) deg[d] = cntL[t] < WEDCAP ? cntL[t] : WEDCAP;
    }
}

// ---------------------------------------------------------------------------
// K_aggout v2 (phase-disjoint fusion — r11 lesson applied):
// Block = 16 dsts (4 waves x 4 dsts). Phase A: each wave runs the r13-proven
// low-VGPR pipelined aggregation for its 4 dsts, writing each finished V row
// to a 4.3-KB LDS tile (68-pad). Barrier. Phase B: wave 0 ONLY loads the
// W_out fragments (live range disjoint from phase A) and runs the proven
// hi/lo MFMA epilogue: out = relu(V@W_out + b_out), direct store.
// __launch_bounds__(256,8) pins VGPR <= 64 so phase B can't cut occupancy.
// ---------------------------------------------------------------------------
__global__ __launch_bounds__(256, 8) void k_aggout(
    const int* __restrict__ deg_arr, const int* __restrict__ slots,
    const float* __restrict__ pos,
    const float* __restrict__ W_pos, const float* __restrict__ b_pos,
    const unsigned* __restrict__ AXb,
    const short* __restrict__ P, const float* __restrict__ b_out,
    float* __restrict__ out)
{
    __shared__ float Vt[16 * 68];      // block V tile, rows padded to 68
    const int lane = threadIdx.x & 63;
    const int wid  = threadIdx.x >> 6;
    const int m = lane & 15, q = lane >> 4;
    const int dbase = blockIdx.x * 16;

    const float wpl0 = W_pos[lane], wpl1 = W_pos[64 + lane], wpl2 = W_pos[128 + lane];
    const float bpl  = b_pos[lane];

    // ---- phase A: aggregate 4 dsts per wave (r13 inner loop verbatim) ----
    #pragma unroll 1
    for (int i = 0; i < 4; ++i) {
        const int d = dbase + wid * 4 + i;
        const float pd0 = pos[d * 3 + 0], pd1 = pos[d * 3 + 1], pd2 = pos[d * 3 + 2];
        const float dlb = fmaf(pd0, wpl0, fmaf(pd1, wpl1, fmaf(pd2, wpl2, bpl)));

        int deg = deg_arr[d]; deg = deg < WEDCAP ? deg : WEDCAP;
        const int* srow = slots + (size_t)d * WEDCAP;

        float Sa = 0.f, Ua = 0.f;
        if (deg > 0) {
            int cs[4], ns[4];
            unsigned cax[4], nax[4];
            {   // prologue: quad 0 -> c-bank
                const int4 qd = *(const int4*)srow;
                cs[0] = qd.x;
                cs[1] = (1 < deg) ? qd.y : qd.x;
                cs[2] = (2 < deg) ? qd.z : qd.x;
                cs[3] = (3 < deg) ? qd.w : qd.x;
                #pragma unroll
                for (int k = 0; k < 4; ++k)
                    cax[k] = AXb[(size_t)cs[k] * 64 + lane];
            }
            for (int j = 0; j < deg; j += 8) {
                if (j + 4 < deg) {   // prefetch quad j+4 -> n-bank
                    const int4 qd = *(const int4*)(srow + j + 4);
                    ns[0] = qd.x;
                    ns[1] = (j + 5 < deg) ? qd.y : qd.x;
                    ns[2] = (j + 6 < deg) ? qd.z : qd.x;
                    ns[3] = (j + 7 < deg) ? qd.w : qd.x;
                    #pragma unroll
                    for (int k = 0; k < 4; ++k)
                        nax[k] = AXb[(size_t)ns[k] * 64 + lane];
                }
                #pragma unroll
                for (int k = 0; k < 4; ++k) {   // compute quad j (c-bank)
                    float wv = __expf(dlb - lo2f(cax[k]));
                    if (j + k >= deg) wv = 0.f;
                    Sa += wv;
                    Ua = fmaf(wv, hi2f(cax[k]) + dlb, Ua);
                }
                if (j + 8 < deg) {   // prefetch quad j+8 -> c-bank
                    const int4 qd = *(const int4*)(srow + j + 8);
                    cs[0] = qd.x;
                    cs[1] = (j + 9  < deg) ? qd.y : qd.x;
                    cs[2] = (j + 10 < deg) ? qd.z : qd.x;
                    cs[3] = (j + 11 < deg) ? qd.w : qd.x;
                    #pragma unroll
                    for (int k = 0; k < 4; ++k)
                        cax[k] = AXb[(size_t)cs[k] * 64 + lane];
                }
                if (j + 4 < deg) {
                    #pragma unroll
                    for (int k = 0; k < 4; ++k) {   // compute quad j+4 (n-bank)
                        float wv = __expf(dlb - lo2f(nax[k]));
                        if (j + 4 + k >= deg) wv = 0.f;
                        Sa += wv;
                        Ua = fmaf(wv, hi2f(nax[k]) + dlb, Ua);
                    }
                }
            }
        }
        Vt[(wid * 4 + i) * 68 + lane] = Ua / (Sa + 1e-16f);
    }
    __syncthreads();

    // ---- phase B: wave 0 runs the output GEMM for the 16-row tile ----
    if (wid == 0) {
        s16x8 Wf[2][4];
        #pragma unroll
        for (int kh = 0; kh < 2; ++kh)
            #pragma unroll
            for (int nt = 0; nt < 4; ++nt)
                Wf[kh][nt] = *(const s16x8*)&P[((size_t)3 * 512 + (kh * 4 + nt) * 64 + lane) * 8];
        float bo[4];
        #pragma unroll
        for (int nt = 0; nt < 4; ++nt) bo[nt] = b_out[nt * 16 + m];

        float vv[16];
        *(float4*)&vv[0]  = *(const float4*)&Vt[m * 68 + q * 8];
        *(float4*)&vv[4]  = *(const float4*)&Vt[m * 68 + q * 8 + 4];
        *(float4*)&vv[8]  = *(const float4*)&Vt[m * 68 + 32 + q * 8];
        *(float4*)&vv[12] = *(const float4*)&Vt[m * 68 + 32 + q * 8 + 4];
        s16x8 ahi0, alo0, ahi1, alo1;
        #pragma unroll
        for (int i = 0; i < 8; ++i) {
            short h, l;
            splitbf(vv[i], h, l);     ahi0[i] = h; alo0[i] = l;
            splitbf(vv[8 + i], h, l); ahi1[i] = h; alo1[i] = l;
        }
        #pragma unroll
        for (int nt = 0; nt < 4; ++nt) {
            f32x4 acc = {0.f, 0.f, 0.f, 0.f};
            acc = __builtin_amdgcn_mfma_f32_16x16x32_bf16(alo0, Wf[0][nt], acc, 0, 0, 0);
            acc = __builtin_amdgcn_mfma_f32_16x16x32_bf16(alo1, Wf[1][nt], acc, 0, 0, 0);
            acc = __builtin_amdgcn_mfma_f32_16x16x32_bf16(ahi0, Wf[0][nt], acc, 0, 0, 0);
            acc = __builtin_amdgcn_mfma_f32_16x16x32_bf16(ahi1, Wf[1][nt], acc, 0, 0, 0);
            #pragma unroll
            for (int r = 0; r < 4; ++r) {
                const float o = acc[r] + bo[nt];
                out[(size_t)(dbase + q * 4 + r) * 64 + nt * 16 + m] = o > 0.f ? o : 0.f;
            }
        }
    }
}

extern "C" void kernel_launch(void* const* d_in, const int* in_sizes, int n_in,
                              void* d_out, int out_size, void* d_ws, size_t ws_size,
                              hipStream_t stream) {
    const float* x     = (const float*)d_in[0];
    const float* pos   = (const float*)d_in[1];
    const int*   ei    = (const int*)d_in[2];
    const float* W_in  = (const float*)d_in[3];
    const float* b_in  = (const float*)d_in[4];
    const float* W_lin = (const float*)d_in[5];
    const float* W_src = (const float*)d_in[6];
    // d_in[7] = W_dst unused: exp(a_dst[i]) is constant within each dst
    // segment and cancels in the softmax normalization.
    const float* W_pos = (const float*)d_in[8];
    const float* b_pos = (const float*)d_in[9];
    const float* W_out = (const float*)d_in[10];
    const float* b_out = (const float*)d_in[11];

    unsigned* AXb   = (unsigned*)d_ws;                          // [N,64] (25.6 MB)
    unsigned* stage = AXb + (size_t)NN * 64;                    // [GA,NWIN,CAP16] (12.8 MB)
    int*      gcnt  = (int*)(stage + (size_t)GA * NWIN * CAP16);// [NWIN,GA] (0.8 MB)
    int*      slots = gcnt + (size_t)NWIN * GA;                 // [NWIN*128,WEDCAP] (16 MB)
    int*      deg   = slots + (size_t)NWIN * 128 * WEDCAP;      // [N]
    int2*     ovf   = (int2*)(deg + NN);                        // [OVFCAP] (1 MB)
    int*      ovfc  = (int*)(ovf + OVFCAP);                     // 1
    short*    P     = (short*)(ovfc + 64);                      // 4*4096 bf16

    k_prep   <<<8,     256, 0, stream>>>(W_in, W_lin, W_src, W_out, P, ovfc);
    k_node_in<<<512,   256, 0, stream>>>(x, P, b_in, pos, W_pos, AXb);
    k_passA  <<<GA,    256, 0, stream>>>(ei, stage, gcnt, ovf, ovfc);
    k_passB  <<<NWIN,  256, 0, stream>>>(stage, gcnt, ovf, ovfc, slots, deg);
    k_aggout <<<NN/16, 256, 0, stream>>>(deg, slots, pos, W_pos, b_pos, AXb, P, b_out, (float*)d_out);
}

// Round 15
// 187.756 us; speedup vs baseline: 1.0296x; 1.0296x over previous
//
#include <hip/hip_runtime.h>

#define NN 100000
#define NE 1250000
#define NWIN 782                      // ceil(NN/128) dst windows of 128 nodes
#define GA 256                        // pass-A writer blocks (private staging columns)
#define CHUNK ((NE + GA - 1) / GA)    // 4883 edges per writer block
#define CAP16 16                      // staging cap per (writer, window) cell (mean 6.2)
#define OVFCAP 131072                 // spill-list capacity (expect ~350 entries)
#define WEDCAP 40                     // max tracked degree per dst (mean 12.5)

typedef __attribute__((ext_vector_type(4))) float f32x4;
typedef __attribute__((ext_vector_type(8))) short s16x8;

// RNE float -> bf16 bits
__device__ __forceinline__ short bfb(float f) {
    union { float f; unsigned u; } c; c.f = f;
    unsigned u = c.u + 0x7fffu + ((c.u >> 16) & 1u);
    return (short)(u >> 16);
}
// hi/lo bf16 split: v ~= hi + lo, residual ~2^-17 * |v|
__device__ __forceinline__ void splitbf(float v, short& hi, short& lo) {
    hi = bfb(v);
    union { unsigned u; float f; } c; c.u = ((unsigned)(unsigned short)hi) << 16;
    lo = bfb(v - c.f);
}
__device__ __forceinline__ float lo2f(unsigned u) {
    union { unsigned u; float f; } c; c.u = u << 16; return c.f;
}
__device__ __forceinline__ float hi2f(unsigned u) {
    union { unsigned u; float f; } c; c.u = u & 0xffff0000u; return c.f;
}

// ---------------------------------------------------------------------------
// K_prep: pack weights into fragment-ordered bf16; zero the spill counter.
// ---------------------------------------------------------------------------
__global__ __launch_bounds__(256) void k_prep(
    const float* __restrict__ Wi, const float* __restrict__ Wl,
    const float* __restrict__ Ws, const float* __restrict__ Wo,
    short* __restrict__ P, int* __restrict__ ovf_cnt)
{
    const int t = blockIdx.x * 256 + threadIdx.x;
    if (t == 0) *ovf_cnt = 0;
    if (t >= 2048) return;
    const int mat = t >> 9, rem = t & 511;
    const int lane = rem & 63, cfg = rem >> 6;
    const int kh = cfg >> 2, nt = cfg & 3;
    const int m = lane & 15, q = lane >> 4;
    const float* W = mat == 0 ? Wi : mat == 1 ? Wl : mat == 2 ? Ws : Wo;
    s16x8 v;
    #pragma unroll
    for (int i = 0; i < 8; ++i)
        v[i] = bfb(W[(kh * 32 + q * 8 + i) * 64 + nt * 16 + m]);
    *(s16x8*)&P[(size_t)t * 8] = v;
}

// ---------------------------------------------------------------------------
// K_front: block-role fusion of two INDEPENDENT stages (disjoint in/out,
// different pipes — r8 validated the mechanism):
//   blocks [0,GA):      passA role (r12-proven writer-major edge binning:
//                       LDS counters, line-exclusive 64-B cells, spill list)
//   blocks [GA,GA+512): node_in role (r13-proven: MFMA h/asrc/xlin GEMMs +
//                       edge-MLP factorization A'=asrc+sp, X'=xlin-sp;
//                       AXb = pack(bf16(A') | bf16(X')<<16))
// ---------------------------------------------------------------------------
__global__ __launch_bounds__(256) void k_front(
    const int* __restrict__ ei, unsigned* __restrict__ stage, int* __restrict__ gcnt,
    int2* __restrict__ ovf, int* __restrict__ ovf_cnt,
    const float* __restrict__ x, const short* __restrict__ P,
    const float* __restrict__ b_in,
    const float* __restrict__ pos, const float* __restrict__ W_pos,
    unsigned* __restrict__ AXb)
{
    __shared__ int lcnt[NWIN];
    __shared__ float hT[4][16 * 68];

    if (blockIdx.x < GA) {
        // ---------------- passA role ----------------
        const int g = blockIdx.x;
        for (int i = threadIdx.x; i < NWIN; i += 256) lcnt[i] = 0;
        __syncthreads();
        unsigned* myStage = stage + (size_t)g * NWIN * CAP16;
        const int e0 = g * CHUNK;
        const int e1 = (e0 + CHUNK < NE) ? e0 + CHUNK : NE;
        for (int e = e0 + threadIdx.x; e < e1; e += 256) {
            const int s = ei[e], d = ei[NE + e];
            const int b = d >> 7;
            const int c = atomicAdd(&lcnt[b], 1);          // LDS atomic
            if (c < CAP16) {
                myStage[b * CAP16 + c] = (unsigned)s | ((unsigned)(d & 127) << 17);
            } else {
                const int o = atomicAdd(ovf_cnt, 1);       // rare (~350 total)
                if (o < OVFCAP) ovf[o] = make_int2(s, d);
            }
        }
        __syncthreads();
        for (int i = threadIdx.x; i < NWIN; i += 256)
            gcnt[i * GA + g] = lcnt[i] < CAP16 ? lcnt[i] : CAP16;
        return;
    }

    // ---------------- node_in role ----------------
    const int lane = threadIdx.x & 63;
    const int wid  = threadIdx.x >> 6;
    const int m = lane & 15, q = lane >> 4;

    s16x8 Wf[3][2][4];
    #pragma unroll
    for (int mat = 0; mat < 3; ++mat)
        #pragma unroll
        for (int kh = 0; kh < 2; ++kh)
            #pragma unroll
            for (int nt = 0; nt < 4; ++nt)
                Wf[mat][kh][nt] = *(const s16x8*)&P[((size_t)mat * 512 + (kh * 4 + nt) * 64 + lane) * 8];
    float bin[4], wpv0[4], wpv1[4], wpv2[4];
    #pragma unroll
    for (int nt = 0; nt < 4; ++nt) {
        bin[nt]  = b_in[nt * 16 + m];
        wpv0[nt] = W_pos[nt * 16 + m];
        wpv1[nt] = W_pos[64 + nt * 16 + m];
        wpv2[nt] = W_pos[128 + nt * 16 + m];
    }

    const int wave = (blockIdx.x - GA) * 4 + wid, nw = (gridDim.x - GA) * 4;
    for (int chunk = wave; chunk < NN / 16; chunk += nw) {
        const int r0 = chunk * 16;
        const float* xr = x + (size_t)(r0 + m) * 64;
        float xv[16];
        *(float4*)&xv[0]  = *(const float4*)(xr + q * 8);
        *(float4*)&xv[4]  = *(const float4*)(xr + q * 8 + 4);
        *(float4*)&xv[8]  = *(const float4*)(xr + 32 + q * 8);
        *(float4*)&xv[12] = *(const float4*)(xr + 32 + q * 8 + 4);
        s16x8 ahi0, alo0, ahi1, alo1;
        #pragma unroll
        for (int i = 0; i < 8; ++i) {
            short h, l;
            splitbf(xv[i], h, l);     ahi0[i] = h; alo0[i] = l;
            splitbf(xv[8 + i], h, l); ahi1[i] = h; alo1[i] = l;
        }
        #pragma unroll
        for (int nt = 0; nt < 4; ++nt) {
            f32x4 acc = {0.f, 0.f, 0.f, 0.f};
            acc = __builtin_amdgcn_mfma_f32_16x16x32_bf16(alo0, Wf[0][0][nt], acc, 0, 0, 0);
            acc = __builtin_amdgcn_mfma_f32_16x16x32_bf16(alo1, Wf[0][1][nt], acc, 0, 0, 0);
            acc = __builtin_amdgcn_mfma_f32_16x16x32_bf16(ahi0, Wf[0][0][nt], acc, 0, 0, 0);
            acc = __builtin_amdgcn_mfma_f32_16x16x32_bf16(ahi1, Wf[0][1][nt], acc, 0, 0, 0);
            #pragma unroll
            for (int r = 0; r < 4; ++r) {
                float hv = acc[r] + bin[nt];
                hT[wid][(q * 4 + r) * 68 + nt * 16 + m] = hv > 0.f ? hv : 0.f;
            }
        }
        float hv[16];
        *(float4*)&hv[0]  = *(const float4*)&hT[wid][m * 68 + q * 8];
        *(float4*)&hv[4]  = *(const float4*)&hT[wid][m * 68 + q * 8 + 4];
        *(float4*)&hv[8]  = *(const float4*)&hT[wid][m * 68 + 32 + q * 8];
        *(float4*)&hv[12] = *(const float4*)&hT[wid][m * 68 + 32 + q * 8 + 4];
        s16x8 hhi0, hlo0, hhi1, hlo1;
        #pragma unroll
        for (int i = 0; i < 8; ++i) {
            short h, l;
            splitbf(hv[i], h, l);     hhi0[i] = h; hlo0[i] = l;
            splitbf(hv[8 + i], h, l); hhi1[i] = h; hlo1[i] = l;
        }
        float px[4], py[4], pz[4];
        #pragma unroll
        for (int r = 0; r < 4; ++r) {
            const float* pp = pos + (size_t)(r0 + q * 4 + r) * 3;
            px[r] = pp[0]; py[r] = pp[1]; pz[r] = pp[2];
        }
        #pragma unroll
        for (int nt = 0; nt < 4; ++nt) {
            f32x4 aS = {0.f, 0.f, 0.f, 0.f}, aL = {0.f, 0.f, 0.f, 0.f};
            aS = __builtin_amdgcn_mfma_f32_16x16x32_bf16(hlo0, Wf[2][0][nt], aS, 0, 0, 0);
            aS = __builtin_amdgcn_mfma_f32_16x16x32_bf16(hlo1, Wf[2][1][nt], aS, 0, 0, 0);
            aS = __builtin_amdgcn_mfma_f32_16x16x32_bf16(hhi0, Wf[2][0][nt], aS, 0, 0, 0);
            aS = __builtin_amdgcn_mfma_f32_16x16x32_bf16(hhi1, Wf[2][1][nt], aS, 0, 0, 0);
            aL = __builtin_amdgcn_mfma_f32_16x16x32_bf16(hlo0, Wf[1][0][nt], aL, 0, 0, 0);
            aL = __builtin_amdgcn_mfma_f32_16x16x32_bf16(hlo1, Wf[1][1][nt], aL, 0, 0, 0);
            aL = __builtin_amdgcn_mfma_f32_16x16x32_bf16(hhi0, Wf[1][0][nt], aL, 0, 0, 0);
            aL = __builtin_amdgcn_mfma_f32_16x16x32_bf16(hhi1, Wf[1][1][nt], aL, 0, 0, 0);
            #pragma unroll
            for (int r = 0; r < 4; ++r) {
                const float sp = fmaf(px[r], wpv0[nt], fmaf(py[r], wpv1[nt], pz[r] * wpv2[nt]));
                const unsigned p = (unsigned)(unsigned short)bfb(aS[r] + sp)          // A'
                                 | ((unsigned)(unsigned short)bfb(aL[r] - sp) << 16); // X'
                AXb[(size_t)(r0 + q * 4 + r) * 64 + nt * 16 + m] = p;
            }
        }
    }
}

// ---------------------------------------------------------------------------
// K_passB (r12-proven): compact writer-major cells + spill list into per-dst
// slot rows in LDS; coalesced int4 dump. Consumer clamps garbage beyond deg.
// ---------------------------------------------------------------------------
__global__ __launch_bounds__(256) void k_passB(
    const unsigned* __restrict__ stage, const int* __restrict__ gcnt,
    const int2* __restrict__ ovf, const int* __restrict__ ovf_cnt,
    int* __restrict__ slots, int* __restrict__ deg)
{
    __shared__ int slotsL[128 * WEDCAP];   // 20480 B
    __shared__ int cntL[128];
    const int b = blockIdx.x;
    const int t = threadIdx.x;
    if (t < 128) cntL[t] = 0;
    __syncthreads();
    const int n = min(gcnt[b * GA + t], CAP16);
    const unsigned* cell = stage + (size_t)t * NWIN * CAP16 + b * CAP16;
    uint4 q0 = *(const uint4*)cell;
    uint4 q1 = *(const uint4*)(cell + 4);
    uint4 q2 = *(const uint4*)(cell + 8);
    uint4 q3 = *(const uint4*)(cell + 12);
    const unsigned eb[16] = {q0.x, q0.y, q0.z, q0.w, q1.x, q1.y, q1.z, q1.w,
                             q2.x, q2.y, q2.z, q2.w, q3.x, q3.y, q3.z, q3.w};
    #pragma unroll
    for (int i = 0; i < CAP16; ++i)
        if (i < n) {
            const int d7 = (int)(eb[i] >> 17);
            const int c = atomicAdd(&cntL[d7], 1);      // LDS atomic, block-local
            if (c < WEDCAP) slotsL[d7 * WEDCAP + c] = (int)(eb[i] & 0x1ffff);
        }
    const int no = min(*ovf_cnt, OVFCAP);
    for (int i = t; i < no; i += 256) {
        const int2 sd = ovf[i];
        if ((sd.y >> 7) == b) {
            const int d7 = sd.y & 127;
            const int c = atomicAdd(&cntL[d7], 1);
            if (c < WEDCAP) slotsL[d7 * WEDCAP + c] = sd.x;
        }
    }
    __syncthreads();
    int4* dstq = (int4*)(slots + (size_t)b * 128 * WEDCAP);
    const int4* srcq = (const int4*)slotsL;
    #pragma unroll
    for (int i = 0; i < 5; ++i) dstq[i * 256 + t] = srcq[i * 256 + t];
    if (t < 128) {
        const int d = (b << 7) + t;
        if (d < NN) deg[d] = cntL[t] < WEDCAP ? cntL[t] : WEDCAP;
    }
}

// ---------------------------------------------------------------------------
// K_agg (r13-proven, VGPR=16/occ=66% — do NOT add register state here):
// wave = dst, register accumulation, pipelined quad banks, factorized MLP.
// Per edge: w = exp(dlb - A'[s]); Sa += w; Ua += w*(X'[s] + dlb).
// ---------------------------------------------------------------------------
__global__ __launch_bounds__(256) void k_agg(
    const int* __restrict__ deg_arr, const int* __restrict__ slots,
    const float* __restrict__ pos,
    const float* __restrict__ W_pos, const float* __restrict__ b_pos,
    const unsigned* __restrict__ AXb, float* __restrict__ V)
{
    const int lane = threadIdx.x & 63;
    const int d = __builtin_amdgcn_readfirstlane((int)((blockIdx.x * 256 + threadIdx.x) >> 6));
    if (d >= NN) return;
    const float pd0 = pos[d * 3 + 0], pd1 = pos[d * 3 + 1], pd2 = pos[d * 3 + 2];
    const float dlb = fmaf(pd0, W_pos[lane],
                      fmaf(pd1, W_pos[64 + lane],
                      fmaf(pd2, W_pos[128 + lane], b_pos[lane])));

    int deg = deg_arr[d]; deg = deg < WEDCAP ? deg : WEDCAP;
    const int* srow = slots + (size_t)d * WEDCAP;

    float Sa = 0.f, Ua = 0.f;
    if (deg > 0) {
        int cs[4], ns[4];
        unsigned cax[4], nax[4];
        {   // prologue: quad 0 -> c-bank
            const int4 qd = *(const int4*)srow;
            cs[0] = qd.x;
            cs[1] = (1 < deg) ? qd.y : qd.x;
            cs[2] = (2 < deg) ? qd.z : qd.x;
            cs[3] = (3 < deg) ? qd.w : qd.x;
            #pragma unroll
            for (int k = 0; k < 4; ++k)
                cax[k] = AXb[(size_t)cs[k] * 64 + lane];
        }
        for (int j = 0; j < deg; j += 8) {
            if (j + 4 < deg) {   // prefetch quad j+4 -> n-bank
                const int4 qd = *(const int4*)(srow + j + 4);
                ns[0] = qd.x;
                ns[1] = (j + 5 < deg) ? qd.y : qd.x;
                ns[2] = (j + 6 < deg) ? qd.z : qd.x;
                ns[3] = (j + 7 < deg) ? qd.w : qd.x;
                #pragma unroll
                for (int k = 0; k < 4; ++k)
                    nax[k] = AXb[(size_t)ns[k] * 64 + lane];
            }
            #pragma unroll
            for (int k = 0; k < 4; ++k) {   // compute quad j (c-bank)
                float wv = __expf(dlb - lo2f(cax[k]));
                if (j + k >= deg) wv = 0.f;
                Sa += wv;
                Ua = fmaf(wv, hi2f(cax[k]) + dlb, Ua);
            }
            if (j + 8 < deg) {   // prefetch quad j+8 -> c-bank
                const int4 qd = *(const int4*)(srow + j + 8);
                cs[0] = qd.x;
                cs[1] = (j + 9  < deg) ? qd.y : qd.x;
                cs[2] = (j + 10 < deg) ? qd.z : qd.x;
                cs[3] = (j + 11 < deg) ? qd.w : qd.x;
                #pragma unroll
                for (int k = 0; k < 4; ++k)
                    cax[k] = AXb[(size_t)cs[k] * 64 + lane];
            }
            if (j + 4 < deg) {
                #pragma unroll
                for (int k = 0; k < 4; ++k) {   // compute quad j+4 (n-bank)
                    float wv = __expf(dlb - lo2f(nax[k]));
                    if (j + 4 + k >= deg) wv = 0.f;
                    Sa += wv;
                    Ua = fmaf(wv, hi2f(nax[k]) + dlb, Ua);
                }
            }
        }
    }
    V[(size_t)d * 64 + lane] = Ua / (Sa + 1e-16f);
}

// ---------------------------------------------------------------------------
// K3 (MFMA): out = relu( V@W_out + b_out ), hi/lo split, weights from P mat 3.
// ---------------------------------------------------------------------------
__global__ __launch_bounds__(256) void k_node_out(
    const float* __restrict__ V, const short* __restrict__ P,
    const float* __restrict__ b_out, float* __restrict__ out)
{
    const int lane = threadIdx.x & 63;
    const int wid  = threadIdx.x >> 6;
    const int m = lane & 15, q = lane >> 4;

    s16x8 Wf[2][4];
    #pragma unroll
    for (int kh = 0; kh < 2; ++kh)
        #pragma unroll
        for (int nt = 0; nt < 4; ++nt)
            Wf[kh][nt] = *(const s16x8*)&P[((size_t)3 * 512 + (kh * 4 + nt) * 64 + lane) * 8];
    float bo[4];
    #pragma unroll
    for (int nt = 0; nt < 4; ++nt) bo[nt] = b_out[nt * 16 + m];

    const int wave = blockIdx.x * 4 + wid, nw = gridDim.x * 4;
    for (int chunk = wave; chunk < NN / 16; chunk += nw) {
        const int r0 = chunk * 16;
        const float* vr = V + (size_t)(r0 + m) * 64;
        float vv[16];
        *(float4*)&vv[0]  = *(const float4*)(vr + q * 8);
        *(float4*)&vv[4]  = *(const float4*)(vr + q * 8 + 4);
        *(float4*)&vv[8]  = *(const float4*)(vr + 32 + q * 8);
        *(float4*)&vv[12] = *(const float4*)(vr + 32 + q * 8 + 4);
        s16x8 ahi0, alo0, ahi1, alo1;
        #pragma unroll
        for (int i = 0; i < 8; ++i) {
            short h, l;
            splitbf(vv[i], h, l);     ahi0[i] = h; alo0[i] = l;
            splitbf(vv[8 + i], h, l); ahi1[i] = h; alo1[i] = l;
        }
        #pragma unroll
        for (int nt = 0; nt < 4; ++nt) {
            f32x4 acc = {0.f, 0.f, 0.f, 0.f};
            acc = __builtin_amdgcn_mfma_f32_16x16x32_bf16(alo0, Wf[0][nt], acc, 0, 0, 0);
            acc = __builtin_amdgcn_mfma_f32_16x16x32_bf16(alo1, Wf[1][nt], acc, 0, 0, 0);
            acc = __builtin_amdgcn_mfma_f32_16x16x32_bf16(ahi0, Wf[0][nt], acc, 0, 0, 0);
            acc = __builtin_amdgcn_mfma_f32_16x16x32_bf16(ahi1, Wf[1][nt], acc, 0, 0, 0);
            #pragma unroll
            for (int r = 0; r < 4; ++r) {
                float o = acc[r] + bo[nt];
                out[(size_t)(r0 + q * 4 + r) * 64 + nt * 16 + m] = o > 0.f ? o : 0.f;
            }
        }
    }
}

extern "C" void kernel_launch(void* const* d_in, const int* in_sizes, int n_in,
                              void* d_out, int out_size, void* d_ws, size_t ws_size,
                              hipStream_t stream) {
    const float* x     = (const float*)d_in[0];
    const float* pos   = (const float*)d_in[1];
    const int*   ei    = (const int*)d_in[2];
    const float* W_in  = (const float*)d_in[3];
    const float* b_in  = (const float*)d_in[4];
    const float* W_lin = (const float*)d_in[5];
    const float* W_src = (const float*)d_in[6];
    // d_in[7] = W_dst unused: exp(a_dst[i]) is constant within each dst
    // segment and cancels in the softmax normalization.
    const float* W_pos = (const float*)d_in[8];
    const float* b_pos = (const float*)d_in[9];
    const float* W_out = (const float*)d_in[10];
    const float* b_out = (const float*)d_in[11];

    unsigned* AXb   = (unsigned*)d_ws;                          // [N,64] (25.6 MB)
    unsigned* stage = AXb + (size_t)NN * 64;                    // [GA,NWIN,CAP16] (12.8 MB)
    int*      gcnt  = (int*)(stage + (size_t)GA * NWIN * CAP16);// [NWIN,GA] (0.8 MB)
    int*      slots = gcnt + (size_t)NWIN * GA;                 // [NWIN*128,WEDCAP] (16 MB)
    int*      deg   = slots + (size_t)NWIN * 128 * WEDCAP;      // [N]
    float*    V     = (float*)(deg + NN);                       // [N,64] (25.6 MB)
    int2*     ovf   = (int2*)(V + (size_t)NN * 64);             // [OVFCAP] (1 MB)
    int*      ovfc  = (int*)(ovf + OVFCAP);                     // 1
    short*    P     = (short*)(ovfc + 64);                      // 4*4096 bf16

    k_prep    <<<8,        256, 0, stream>>>(W_in, W_lin, W_src, W_out, P, ovfc);
    k_front   <<<GA + 512, 256, 0, stream>>>(ei, stage, gcnt, ovf, ovfc,
                                             x, P, b_in, pos, W_pos, AXb);
    k_passB   <<<NWIN,     256, 0, stream>>>(stage, gcnt, ovf, ovfc, slots, deg);
    k_agg     <<<(NN + 3) / 4, 256, 0, stream>>>(deg, slots, pos, W_pos, b_pos, AXb, V);
    k_node_out<<<512,      256, 0, stream>>>(V, P, b_out, (float*)d_out);
}